// Round 3
// baseline (326.765 us; speedup 1.0000x reference)
//
#include <hip/hip_runtime.h>

// Residual GCN, MI355X. B=8, N=2048, D=128 fixed. External dtype fp32.
// out = dinv_i * (A @ (dinv_j * leakyrelu(X@W + b))) [+ X]
// Internal pipeline bf16 + MFMA 16x16x32 bf16, fp32 accumulate.
//
// R11: k_gah restructure. R10 post-mortem: staged B tile has ZERO cross-wave
//  reuse (each of 128 B rows is consumed by exactly one wave), so B-via-LDS
//  only cost 8 extra LDS ops + a mid-step vmcnt stall before its ds_writes
//  (13 LDS ops per 8 MFMAs). New k_gah: A stays in LDS (real 4x sharing,
//  double-buffered, 1 barrier/step, reg-staged with a full-step-early load);
//  B streams global->register with depth-2 NAMED-register prefetch (p/r
//  sets, unroll-2 - no runtime-indexed arrays). Per-wave LDS ops 13 -> 5
//  per 8 MFMAs. Unlike R9 (depth-1 ~40cyc cover, no barriers, 2 waves/SIMD),
//  B loads here are issued a full step (~250-400cyc) before use and the
//  A-barrier keeps the 2-blocks/CU co-resident overlap (m97 mechanism).
//  k_pre / k_gxw unchanged from R10 (isolate the variable).
// Numerics identical to R4/R9/R10 (same accumulation order / bf16 casts).

typedef short bf16x8 __attribute__((ext_vector_type(8)));
typedef float f32x4 __attribute__((ext_vector_type(4)));

static __device__ __forceinline__ float bf2f(unsigned short h) {
    union { unsigned int u; float f; } v; v.u = ((unsigned int)h) << 16; return v.f;
}
static __device__ __forceinline__ unsigned short f2bf(float x) {  // RNE
    union { float f; unsigned int u; } v; v.f = x;
    return (unsigned short)((v.u + 0x7FFFu + ((v.u >> 16) & 1u)) >> 16);
}

// ---- fused: adj rowsum -> dinv, adj fp32 -> bf16, W transpose, bias ------
__global__ __launch_bounds__(256) void k_pre(const float* __restrict__ adj,
                                             const float* __restrict__ W1,
                                             const float* __restrict__ W2,
                                             const float* __restrict__ W3,
                                             const float* __restrict__ b1,
                                             const float* __restrict__ b2,
                                             const float* __restrict__ b3,
                                             float* __restrict__ dinv,
                                             unsigned short* __restrict__ adjb,
                                             unsigned short* __restrict__ WT,
                                             float* __restrict__ biasf) {
    if (blockIdx.x >= 16384) {                        // prep tail: W^T + bias
        const int e = (blockIdx.x - 16384) * 256 + threadIdx.x;
        if (e < 49152) {
            const int w = e >> 14, r = e & 16383;
            const int f = r & 127, k = r >> 7;
            const float* W = (w == 0) ? W1 : ((w == 1) ? W2 : W3);
            WT[w * 16384 + f * 128 + k] = f2bf(W[r]);
        } else if (e < 49536) {
            const int idx = e - 49152;
            const float* bp = (idx < 128) ? b1 : ((idx < 256) ? b2 : b3);
            biasf[idx] = bp[idx & 127];
        }
        return;
    }
    const int row = blockIdx.x;                       // 0..16383
    const size_t base = (size_t)row * 2048 + threadIdx.x * 8;
    const float4 a = *(const float4*)(adj + base);
    const float4 b = *(const float4*)(adj + base + 4);
    float s = a.x + a.y + a.z + a.w + b.x + b.y + b.z + b.w;
    union { uint4 u; unsigned short h[8]; } pk;
    pk.h[0] = f2bf(a.x); pk.h[1] = f2bf(a.y); pk.h[2] = f2bf(a.z); pk.h[3] = f2bf(a.w);
    pk.h[4] = f2bf(b.x); pk.h[5] = f2bf(b.y); pk.h[6] = f2bf(b.z); pk.h[7] = f2bf(b.w);
    *(uint4*)(adjb + base) = pk.u;
#pragma unroll
    for (int off = 32; off > 0; off >>= 1) s += __shfl_down(s, off);
    __shared__ float ws[4];
    if ((threadIdx.x & 63) == 0) ws[threadIdx.x >> 6] = s;
    __syncthreads();
    if (threadIdx.x == 0) {
        float t = ws[0] + ws[1] + ws[2] + ws[3];
        dinv[row] = (t > 0.f) ? rsqrtf(t) : 0.f;      // matches where(isinf,0)
    }
}

// ---- small GEMM: Hs = leakyrelu(X @ W + b) * dinv_j -> HsT (transposed) --
// Stage full 128x128 WT in LDS once (one barrier), then barrier-free MFMA.
// 512 blocks x 4 waves; block = 32 rows; wave = 16 rows x 64 f.
template <int AEXT>
__global__ __launch_bounds__(256) void k_gxw(const void* __restrict__ Asrc,
                                             const unsigned short* __restrict__ WTb,
                                             const float* __restrict__ biasf,
                                             const float* __restrict__ dinv,
                                             unsigned short* __restrict__ HsT) {
    constexpr int LDK = 136;                          // 128 + 8 pad
    __shared__ unsigned short Bs[128 * LDK];          // 34 KB

    const int tid  = threadIdx.x;
    const int wave = tid >> 6;
    const int lane = tid & 63;
    const int n_   = lane & 15;
    const int q    = lane >> 4;
    const int wm   = wave >> 1;                       // row half 0..1
    const int ch   = wave & 1;                        // col half 0..1

    const int r0 = blockIdx.x * 32;                   // 512 blocks

#pragma unroll
    for (int it = 0; it < 8; ++it) {                  // stage full 128x128 WT
        int task = tid + it * 256;
        int f  = task >> 4;
        int cj = (task & 15) * 8;
        *(uint4*)(&Bs[f * LDK + cj]) = *(const uint4*)(WTb + f * 128 + cj);
    }
    __syncthreads();

    const int arow = r0 + wm * 16 + n_;
    bf16x8 av[4];
#pragma unroll
    for (int s = 0; s < 4; ++s) {
        if (AEXT) {
            const float* p = (const float*)Asrc + (size_t)arow * 128 + s * 32 + q * 8;
            float4 uu = ((const float4*)p)[0], w = ((const float4*)p)[1];
            union { bf16x8 v; unsigned short h[8]; } r;
            r.h[0] = f2bf(uu.x); r.h[1] = f2bf(uu.y); r.h[2] = f2bf(uu.z); r.h[3] = f2bf(uu.w);
            r.h[4] = f2bf(w.x);  r.h[5] = f2bf(w.y);  r.h[6] = f2bf(w.z);  r.h[7] = f2bf(w.w);
            av[s] = r.v;
        } else {
            av[s] = *(const bf16x8*)((const unsigned short*)Asrc + (size_t)arow * 128 + s * 32 + q * 8);
        }
    }

    f32x4 acc[4];
#pragma unroll
    for (int i = 0; i < 4; ++i) acc[i] = (f32x4){0.f, 0.f, 0.f, 0.f};
#pragma unroll
    for (int s = 0; s < 4; ++s) {
#pragma unroll
        for (int nt = 0; nt < 4; ++nt) {
            bf16x8 bv = *(const bf16x8*)(&Bs[(ch * 64 + nt * 16 + n_) * LDK + s * 32 + q * 8]);
            acc[nt] = __builtin_amdgcn_mfma_f32_16x16x32_bf16(av[s], bv, acc[nt], 0, 0, 0);
        }
    }

    // C/D: col = lane&15, row = quad*4 + reg
    const int rbase = r0 + wm * 16 + q * 4;
    float dsc[4];
#pragma unroll
    for (int r = 0; r < 4; ++r) dsc[r] = dinv[rbase + r];
    const int b  = rbase >> 11;
    const int jb = rbase & 2047;
    unsigned short* Hb = HsT + (size_t)b * (128 * 2048);
#pragma unroll
    for (int nt = 0; nt < 4; ++nt) {
        const int f = ch * 64 + nt * 16 + n_;
        const float bf = biasf[f];
        unsigned short pk[4];
#pragma unroll
        for (int r = 0; r < 4; ++r) {
            float v = acc[nt][r] + bf;
            v = (v > 0.f) ? v : 0.01f * v;            // LeakyReLU(0.01)
            pk[r] = f2bf(v * dsc[r]);                 // * dinv_j
        }
        uint2 uo;
        uo.x = (unsigned int)pk[0] | ((unsigned int)pk[1] << 16);
        uo.y = (unsigned int)pk[2] | ((unsigned int)pk[3] << 16);
        *(uint2*)(Hb + (size_t)f * 2048 + jb) = uo;   // HsT[b][f][j]
    }
}

// ---- big GEMM: out = (adjb @ HsT^T) * dinv_i [+resid] --------------------
// 512 blocks (2/CU), block = 32 rows x 128 f, K = 2048 in 32 steps of 64.
// A in LDS (4x shared, padded, double-buffered, reg-staged one step early,
// ONE barrier per step). B direct global->reg, depth-2 named-reg prefetch
// (sets p=even tiles, r=odd tiles; reload right after consumption so loads
// have ~2 steps in flight, modulo the __syncthreads vmcnt drain which still
// leaves ~1 full step of cover). Wave w: 32 rows x 32 f, acc 2x2 frags.
// MODE 1: store (*dinv_i); MODE 2: +resid. OUT32: fp32 store else bf16.
template <int MODE, int OUT32>
__global__ __launch_bounds__(256) void k_gah(const unsigned short* __restrict__ adjb,
                                             const unsigned short* __restrict__ HsT,
                                             const float* __restrict__ dinv,
                                             const unsigned short* __restrict__ resid,
                                             void* __restrict__ outp) {
    constexpr int LDK = 72;                           // 64 + 8 pad
    constexpr int ASZ = 32 * LDK;                     // elems per A buffer
    __shared__ unsigned short Sm[2 * ASZ];            // 9 KB

    const int tid  = threadIdx.x;
    const int wave = tid >> 6;
    const int lane = tid & 63;
    const int n_   = lane & 15;
    const int q    = lane >> 4;

    const int bb = blockIdx.x;                        // 512 blocks
    const int b  = bb & 7;                            // batch -> XCD affinity
    const int rt = bb >> 3;                           // 0..63
    const int row0 = b * 2048 + rt * 32;

    const unsigned short* Ag = adjb + (size_t)row0 * 2048;
    const unsigned short* Bg = HsT + (size_t)b * (128 * 2048);

    // A staging: thread t -> row t>>3, col chunk (t&7)*8
    const int srow = tid >> 3;
    const int sc   = (tid & 7) * 8;
    const unsigned short* As = Ag + (size_t)srow * 2048 + sc;
    const int dA = srow * LDK + sc;

    // B frag pointers (per-wave-private rows f = wave*32 + {0,16} + n_)
    const unsigned short* Bp0 = Bg + (size_t)(wave * 32 + n_) * 2048 + q * 8;
    const unsigned short* Bp1 = Bp0 + 16 * 2048;

    f32x4 acc[2][2];
#pragma unroll
    for (int i = 0; i < 2; ++i)
#pragma unroll
        for (int j = 0; j < 2; ++j) acc[i][j] = (f32x4){0.f, 0.f, 0.f, 0.f};

    // prologue: stage A tile0 directly; preload A tiles 1,2 and B tiles 0,1
    {
        uint4 t0 = *(const uint4*)(As);
        *(uint4*)(&Sm[dA]) = t0;
    }
    uint4 rA0 = *(const uint4*)(As + 64);             // A tile 1 (even writes)
    uint4 rA1 = *(const uint4*)(As + 128);            // A tile 2 (odd writes)
    bf16x8 p00 = *(const bf16x8*)(Bp0);               // B tile 0 (even)
    bf16x8 p01 = *(const bf16x8*)(Bp0 + 32);
    bf16x8 p02 = *(const bf16x8*)(Bp1);
    bf16x8 p03 = *(const bf16x8*)(Bp1 + 32);
    bf16x8 r00 = *(const bf16x8*)(Bp0 + 64);          // B tile 1 (odd)
    bf16x8 r01 = *(const bf16x8*)(Bp0 + 96);
    bf16x8 r02 = *(const bf16x8*)(Bp1 + 64);
    bf16x8 r03 = *(const bf16x8*)(Bp1 + 96);
    __syncthreads();

    const int aoff = n_ * LDK + q * 8;

#pragma unroll 1
    for (int kc = 0; kc < 32; kc += 2) {
        // ---- even step: compute tile kc from buf0 with p-set -------------
        {
            *(uint4*)(&Sm[ASZ + dA]) = rA0;           // write A tile kc+1
            if (kc < 29) rA0 = *(const uint4*)(As + (kc + 3) * 64);
            const unsigned short* sb = &Sm[0];
            bf16x8 a00 = *(const bf16x8*)(&sb[aoff]);
            bf16x8 a10 = *(const bf16x8*)(&sb[aoff + 16 * LDK]);
            bf16x8 a01 = *(const bf16x8*)(&sb[aoff + 32]);
            bf16x8 a11 = *(const bf16x8*)(&sb[aoff + 16 * LDK + 32]);
            acc[0][0] = __builtin_amdgcn_mfma_f32_16x16x32_bf16(a00, p00, acc[0][0], 0, 0, 0);
            acc[1][0] = __builtin_amdgcn_mfma_f32_16x16x32_bf16(a10, p00, acc[1][0], 0, 0, 0);
            acc[0][1] = __builtin_amdgcn_mfma_f32_16x16x32_bf16(a00, p02, acc[0][1], 0, 0, 0);
            acc[1][1] = __builtin_amdgcn_mfma_f32_16x16x32_bf16(a10, p02, acc[1][1], 0, 0, 0);
            acc[0][0] = __builtin_amdgcn_mfma_f32_16x16x32_bf16(a01, p01, acc[0][0], 0, 0, 0);
            acc[1][0] = __builtin_amdgcn_mfma_f32_16x16x32_bf16(a11, p01, acc[1][0], 0, 0, 0);
            acc[0][1] = __builtin_amdgcn_mfma_f32_16x16x32_bf16(a01, p03, acc[0][1], 0, 0, 0);
            acc[1][1] = __builtin_amdgcn_mfma_f32_16x16x32_bf16(a11, p03, acc[1][1], 0, 0, 0);
            if (kc < 30) {                            // reload p <- tile kc+2
                p00 = *(const bf16x8*)(Bp0 + (kc + 2) * 64);
                p01 = *(const bf16x8*)(Bp0 + (kc + 2) * 64 + 32);
                p02 = *(const bf16x8*)(Bp1 + (kc + 2) * 64);
                p03 = *(const bf16x8*)(Bp1 + (kc + 2) * 64 + 32);
            }
            __syncthreads();
        }
        // ---- odd step: compute tile kc+1 from buf1 with r-set ------------
        {
            if (kc < 30) {
                *(uint4*)(&Sm[dA]) = rA1;             // write A tile kc+2
                if (kc < 28) rA1 = *(const uint4*)(As + (kc + 4) * 64);
            }
            const unsigned short* sb = &Sm[ASZ];
            bf16x8 a00 = *(const bf16x8*)(&sb[aoff]);
            bf16x8 a10 = *(const bf16x8*)(&sb[aoff + 16 * LDK]);
            bf16x8 a01 = *(const bf16x8*)(&sb[aoff + 32]);
            bf16x8 a11 = *(const bf16x8*)(&sb[aoff + 16 * LDK + 32]);
            acc[0][0] = __builtin_amdgcn_mfma_f32_16x16x32_bf16(a00, r00, acc[0][0], 0, 0, 0);
            acc[1][0] = __builtin_amdgcn_mfma_f32_16x16x32_bf16(a10, r00, acc[1][0], 0, 0, 0);
            acc[0][1] = __builtin_amdgcn_mfma_f32_16x16x32_bf16(a00, r02, acc[0][1], 0, 0, 0);
            acc[1][1] = __builtin_amdgcn_mfma_f32_16x16x32_bf16(a10, r02, acc[1][1], 0, 0, 0);
            acc[0][0] = __builtin_amdgcn_mfma_f32_16x16x32_bf16(a01, r01, acc[0][0], 0, 0, 0);
            acc[1][0] = __builtin_amdgcn_mfma_f32_16x16x32_bf16(a11, r01, acc[1][0], 0, 0, 0);
            acc[0][1] = __builtin_amdgcn_mfma_f32_16x16x32_bf16(a01, r03, acc[0][1], 0, 0, 0);
            acc[1][1] = __builtin_amdgcn_mfma_f32_16x16x32_bf16(a11, r03, acc[1][1], 0, 0, 0);
            if (kc < 29) {                            // reload r <- tile kc+3
                r00 = *(const bf16x8*)(Bp0 + (kc + 3) * 64);
                r01 = *(const bf16x8*)(Bp0 + (kc + 3) * 64 + 32);
                r02 = *(const bf16x8*)(Bp1 + (kc + 3) * 64);
                r03 = *(const bf16x8*)(Bp1 + (kc + 3) * 64 + 32);
            }
            __syncthreads();
        }
    }

    // epilogue. C/D: col = lane&15, row = quad*4 + reg
    const int rb = row0 + q * 4;
    float dsc[2][4];
#pragma unroll
    for (int mi = 0; mi < 2; ++mi)
#pragma unroll
        for (int r = 0; r < 4; ++r) dsc[mi][r] = dinv[rb + mi * 16 + r];
#pragma unroll
    for (int mi = 0; mi < 2; ++mi) {
#pragma unroll
        for (int nj = 0; nj < 2; ++nj) {
            const int f = wave * 32 + nj * 16 + n_;
#pragma unroll
            for (int r = 0; r < 4; ++r) {
                const size_t gr = (size_t)(rb + mi * 16 + r);
                float v = acc[mi][nj][r] * dsc[mi][r];    // * dinv_i
                if (MODE == 2) v += bf2f(resid[gr * 128 + f]);
                if (OUT32) ((float*)outp)[gr * 128 + f] = v;
                else ((unsigned short*)outp)[gr * 128 + f] = f2bf(v);
            }
        }
    }
}

extern "C" void kernel_launch(void* const* d_in, const int* in_sizes, int n_in,
                              void* d_out, int out_size, void* d_ws, size_t ws_size,
                              hipStream_t stream) {
    const float* X   = (const float*)d_in[0];
    const float* adj = (const float*)d_in[1];
    const float* W1  = (const float*)d_in[2];
    const float* b1  = (const float*)d_in[3];
    const float* W2  = (const float*)d_in[4];
    const float* b2  = (const float*)d_in[5];
    const float* W3  = (const float*)d_in[6];
    const float* b3  = (const float*)d_in[7];

    // ws: adjb @0 (64 MiB) | dinv @64M (64K) | biasf @64M+64K | WT @64M+128K
    //     (96K) | HsT @64M+256K (4M) | Xa @68M+256K (4M) | X2 @72M+256K (4M)
    char* ws = (char*)d_ws;
    unsigned short* adjb  = (unsigned short*)ws;
    float*          dinv  = (float*)(ws + (64u << 20));
    float*          biasf = (float*)(ws + (64u << 20) + (64u << 10));
    unsigned short* WT    = (unsigned short*)(ws + (64u << 20) + (128u << 10));
    unsigned short* HsT   = (unsigned short*)(ws + (64u << 20) + (256u << 10));
    unsigned short* Xa    = (unsigned short*)(ws + (68u << 20) + (256u << 10));
    unsigned short* X2    = (unsigned short*)(ws + (72u << 20) + (256u << 10));

    k_pre<<<16578, 256, 0, stream>>>(adj, W1, W2, W3, b1, b2, b3, dinv, adjb, WT, biasf);

    // layer 1
    k_gxw<1><<<512, 256, 0, stream>>>(X, WT, biasf, dinv, HsT);
    k_gah<1, 0><<<512, 256, 0, stream>>>(adjb, HsT, dinv, nullptr, Xa);
    // layer 2 (residual = Xa)
    k_gxw<0><<<512, 256, 0, stream>>>(Xa, WT + 16384, biasf + 128, dinv, HsT);
    k_gah<2, 0><<<512, 256, 0, stream>>>(adjb, HsT, dinv, Xa, X2);
    // layer 3 -> fp32 out
    k_gxw<0><<<512, 256, 0, stream>>>(X2, WT + 32768, biasf + 256, dinv, HsT);
    k_gah<1, 1><<<512, 256, 0, stream>>>(adjb, HsT, dinv, nullptr, (float*)d_out);
}

// Round 4
// 277.651 us; speedup vs baseline: 1.1769x; 1.1769x over previous
//
#include <hip/hip_runtime.h>

// Residual GCN, MI355X. B=8, N=2048, D=128 fixed. External dtype fp32.
// out = dinv_i * (A @ (dinv_j * leakyrelu(X@W + b))) [+ X]
// Internal pipeline bf16 + MFMA 16x16x32 bf16, fp32 accumulate.
//
// R12: k_gah -> counted-vmcnt pipeline (T3/T4). R11 post-mortem: ANY global
//  load issued near a __syncthreads gets drained by the compiler's
//  s_waitcnt vmcnt(0) before s_barrier -> zero prefetch cover; that drain
//  x32 steps is the k_gah cost (~55-80us vs ~13us floor). New k_gah:
//   - staging via global_load_lds width=16 (no VGPR round trip; 5 staging
//     instrs/wave/step: 1 A + 4 B),
//   - THREE LDS buffers (60KB), raw s_barrier + inline-asm
//     s_waitcnt vmcnt(10): stage(t+1),(t+2) stay IN FLIGHT across barriers,
//     ~2 steps (~600cyc) of latency cover,
//   - rule 21: global_load_lds writes linearly, so bank-conflict fix is
//     pre-swizzled GLOBAL source (16B-chunk index ^= row&7) + same swizzle
//     on ds_read; wave's read then hits all 32 banks exactly 8x (uniform).
//   - tail: stages wrap ((t+3)&31) into the just-freed buffer to keep
//     vmcnt bookkeeping uniform (3 wasted 20KB stages, ~1us L2).
//  Schedule/iter: waitcnt vmcnt(10); s_barrier; ds_read+MFMA; s_barrier;
//  stage(t+3)->buf[t%3]. Second barrier protects same-buffer overwrite.
//  k_pre / k_gxw unchanged from R10 (isolate the variable).
// Numerics identical to R4..R11 (same accumulation order / bf16 casts).

typedef short bf16x8 __attribute__((ext_vector_type(8)));
typedef float f32x4 __attribute__((ext_vector_type(4)));

static __device__ __forceinline__ float bf2f(unsigned short h) {
    union { unsigned int u; float f; } v; v.u = ((unsigned int)h) << 16; return v.f;
}
static __device__ __forceinline__ unsigned short f2bf(float x) {  // RNE
    union { float f; unsigned int u; } v; v.f = x;
    return (unsigned short)((v.u + 0x7FFFu + ((v.u >> 16) & 1u)) >> 16);
}

static __device__ __forceinline__ void gl2lds16(const unsigned short* g,
                                                unsigned short* l) {
    __builtin_amdgcn_global_load_lds(
        (const __attribute__((address_space(1))) unsigned int*)g,
        (__attribute__((address_space(3))) unsigned int*)l, 16, 0, 0);
}

// ---- fused: adj rowsum -> dinv, adj fp32 -> bf16, W transpose, bias ------
__global__ __launch_bounds__(256) void k_pre(const float* __restrict__ adj,
                                             const float* __restrict__ W1,
                                             const float* __restrict__ W2,
                                             const float* __restrict__ W3,
                                             const float* __restrict__ b1,
                                             const float* __restrict__ b2,
                                             const float* __restrict__ b3,
                                             float* __restrict__ dinv,
                                             unsigned short* __restrict__ adjb,
                                             unsigned short* __restrict__ WT,
                                             float* __restrict__ biasf) {
    if (blockIdx.x >= 16384) {                        // prep tail: W^T + bias
        const int e = (blockIdx.x - 16384) * 256 + threadIdx.x;
        if (e < 49152) {
            const int w = e >> 14, r = e & 16383;
            const int f = r & 127, k = r >> 7;
            const float* W = (w == 0) ? W1 : ((w == 1) ? W2 : W3);
            WT[w * 16384 + f * 128 + k] = f2bf(W[r]);
        } else if (e < 49536) {
            const int idx = e - 49152;
            const float* bp = (idx < 128) ? b1 : ((idx < 256) ? b2 : b3);
            biasf[idx] = bp[idx & 127];
        }
        return;
    }
    const int row = blockIdx.x;                       // 0..16383
    const size_t base = (size_t)row * 2048 + threadIdx.x * 8;
    const float4 a = *(const float4*)(adj + base);
    const float4 b = *(const float4*)(adj + base + 4);
    float s = a.x + a.y + a.z + a.w + b.x + b.y + b.z + b.w;
    union { uint4 u; unsigned short h[8]; } pk;
    pk.h[0] = f2bf(a.x); pk.h[1] = f2bf(a.y); pk.h[2] = f2bf(a.z); pk.h[3] = f2bf(a.w);
    pk.h[4] = f2bf(b.x); pk.h[5] = f2bf(b.y); pk.h[6] = f2bf(b.z); pk.h[7] = f2bf(b.w);
    *(uint4*)(adjb + base) = pk.u;
#pragma unroll
    for (int off = 32; off > 0; off >>= 1) s += __shfl_down(s, off);
    __shared__ float ws[4];
    if ((threadIdx.x & 63) == 0) ws[threadIdx.x >> 6] = s;
    __syncthreads();
    if (threadIdx.x == 0) {
        float t = ws[0] + ws[1] + ws[2] + ws[3];
        dinv[row] = (t > 0.f) ? rsqrtf(t) : 0.f;      // matches where(isinf,0)
    }
}

// ---- small GEMM: Hs = leakyrelu(X @ W + b) * dinv_j -> HsT (transposed) --
// Stage full 128x128 WT in LDS once (one barrier), then barrier-free MFMA.
// 512 blocks x 4 waves; block = 32 rows; wave = 16 rows x 64 f.
template <int AEXT>
__global__ __launch_bounds__(256) void k_gxw(const void* __restrict__ Asrc,
                                             const unsigned short* __restrict__ WTb,
                                             const float* __restrict__ biasf,
                                             const float* __restrict__ dinv,
                                             unsigned short* __restrict__ HsT) {
    constexpr int LDK = 136;                          // 128 + 8 pad
    __shared__ unsigned short Bs[128 * LDK];          // 34 KB

    const int tid  = threadIdx.x;
    const int wave = tid >> 6;
    const int lane = tid & 63;
    const int n_   = lane & 15;
    const int q    = lane >> 4;
    const int wm   = wave >> 1;                       // row half 0..1
    const int ch   = wave & 1;                        // col half 0..1

    const int r0 = blockIdx.x * 32;                   // 512 blocks

#pragma unroll
    for (int it = 0; it < 8; ++it) {                  // stage full 128x128 WT
        int task = tid + it * 256;
        int f  = task >> 4;
        int cj = (task & 15) * 8;
        *(uint4*)(&Bs[f * LDK + cj]) = *(const uint4*)(WTb + f * 128 + cj);
    }
    __syncthreads();

    const int arow = r0 + wm * 16 + n_;
    bf16x8 av[4];
#pragma unroll
    for (int s = 0; s < 4; ++s) {
        if (AEXT) {
            const float* p = (const float*)Asrc + (size_t)arow * 128 + s * 32 + q * 8;
            float4 uu = ((const float4*)p)[0], w = ((const float4*)p)[1];
            union { bf16x8 v; unsigned short h[8]; } r;
            r.h[0] = f2bf(uu.x); r.h[1] = f2bf(uu.y); r.h[2] = f2bf(uu.z); r.h[3] = f2bf(uu.w);
            r.h[4] = f2bf(w.x);  r.h[5] = f2bf(w.y);  r.h[6] = f2bf(w.z);  r.h[7] = f2bf(w.w);
            av[s] = r.v;
        } else {
            av[s] = *(const bf16x8*)((const unsigned short*)Asrc + (size_t)arow * 128 + s * 32 + q * 8);
        }
    }

    f32x4 acc[4];
#pragma unroll
    for (int i = 0; i < 4; ++i) acc[i] = (f32x4){0.f, 0.f, 0.f, 0.f};
#pragma unroll
    for (int s = 0; s < 4; ++s) {
#pragma unroll
        for (int nt = 0; nt < 4; ++nt) {
            bf16x8 bv = *(const bf16x8*)(&Bs[(ch * 64 + nt * 16 + n_) * LDK + s * 32 + q * 8]);
            acc[nt] = __builtin_amdgcn_mfma_f32_16x16x32_bf16(av[s], bv, acc[nt], 0, 0, 0);
        }
    }

    // C/D: col = lane&15, row = quad*4 + reg
    const int rbase = r0 + wm * 16 + q * 4;
    float dsc[4];
#pragma unroll
    for (int r = 0; r < 4; ++r) dsc[r] = dinv[rbase + r];
    const int b  = rbase >> 11;
    const int jb = rbase & 2047;
    unsigned short* Hb = HsT + (size_t)b * (128 * 2048);
#pragma unroll
    for (int nt = 0; nt < 4; ++nt) {
        const int f = ch * 64 + nt * 16 + n_;
        const float bf = biasf[f];
        unsigned short pk[4];
#pragma unroll
        for (int r = 0; r < 4; ++r) {
            float v = acc[nt][r] + bf;
            v = (v > 0.f) ? v : 0.01f * v;            // LeakyReLU(0.01)
            pk[r] = f2bf(v * dsc[r]);                 // * dinv_j
        }
        uint2 uo;
        uo.x = (unsigned int)pk[0] | ((unsigned int)pk[1] << 16);
        uo.y = (unsigned int)pk[2] | ((unsigned int)pk[3] << 16);
        *(uint2*)(Hb + (size_t)f * 2048 + jb) = uo;   // HsT[b][f][j]
    }
}

// ---- big GEMM: out = (adjb @ HsT^T) * dinv_i [+resid] --------------------
// 512 blocks (2/CU), block = 32 rows x 128 f, K = 2048 in 32 steps of 64.
// global_load_lds staging, 3 LDS buffers, counted vmcnt(10), raw barriers.
// LDS tile layout (per buffer, 20KB): A[32 rows][64k] then B[128 rows][64k],
// linear rows (128B/row), 16B-chunk index XOR'd with (row&7) on BOTH the
// global source (pre-swizzle) and the ds_read address.
// Wave w: 32 rows x 32 f (f in [w*32,w*32+32)), acc 2x2 16x16 frags.
// MODE 1: store (*dinv_i); MODE 2: +resid. OUT32: fp32 store else bf16.
template <int MODE, int OUT32>
__global__ __launch_bounds__(256, 2) void k_gah(const unsigned short* __restrict__ adjb,
                                                const unsigned short* __restrict__ HsT,
                                                const float* __restrict__ dinv,
                                                const unsigned short* __restrict__ resid,
                                                void* __restrict__ outp) {
    constexpr int BUFE = 10240;                       // elems per buffer (20KB)
    __shared__ unsigned short Sm[3 * BUFE];           // 60KB

    const int tid  = threadIdx.x;
    const int wave = tid >> 6;
    const int lane = tid & 63;
    const int n_   = lane & 15;
    const int q    = lane >> 4;

    const int bb = blockIdx.x;                        // 512 blocks
    const int b  = bb & 7;                            // batch -> XCD affinity
    const int rt = bb >> 3;                           // 0..63
    const int row0 = b * 2048 + rt * 32;

    const unsigned short* Ag = adjb + (size_t)row0 * 2048;
    const unsigned short* Bg = HsT + (size_t)b * (128 * 2048);

    // --- staging geometry (global_load_lds: lane l -> wavebase + l*16B) ---
    // LDS linear decode within a 1KB wave-chunk: row_sub = l>>3, chunk = l&7.
    // Pre-swizzled source chunk = (l&7) ^ (l>>3)  [row&7 == l>>3 everywhere].
    const int lr  = lane >> 3;                        // 0..7
    const int sch = (lane & 7) ^ lr;                  // swizzled src chunk
    // A: wave w covers tile rows w*8 + lr. B (i=0..3): rows w*32 + i*8 + lr.
    const unsigned short* Asg = Ag + (size_t)(wave * 8 + lr) * 2048 + sch * 8;
    const unsigned short* Bsg0 = Bg + (size_t)(wave * 32 + 0 + lr) * 2048 + sch * 8;
    const unsigned short* Bsg1 = Bsg0 + 8 * 2048;
    const unsigned short* Bsg2 = Bsg0 + 16 * 2048;
    const unsigned short* Bsg3 = Bsg0 + 24 * 2048;
    // LDS dest bases (elements, wave-uniform): A at wave*512; B at
    // 2048 + wave*2048 + i*512.
    const int dstA = wave * 512;
    const int dstB = 2048 + wave * 2048;

    // --- read geometry (swizzled ds_read) ---------------------------------
    // frag (row, s): elem off = row*64 + (((s*4+q) ^ (row&7)) * 8); B +2048.
    const int swz = n_ & 7;
    int aoff[2][2], boff[2][2];
#pragma unroll
    for (int mi = 0; mi < 2; ++mi)
#pragma unroll
        for (int s = 0; s < 2; ++s)
            aoff[mi][s] = (n_ + mi * 16) * 64 + (((s * 4 + q) ^ swz) * 8);
#pragma unroll
    for (int nj = 0; nj < 2; ++nj)
#pragma unroll
        for (int s = 0; s < 2; ++s)
            boff[nj][s] = 2048 + (wave * 32 + nj * 16 + n_) * 64 + (((s * 4 + q) ^ swz) * 8);

    f32x4 acc[2][2];
#pragma unroll
    for (int i = 0; i < 2; ++i)
#pragma unroll
        for (int j = 0; j < 2; ++j) acc[i][j] = (f32x4){0.f, 0.f, 0.f, 0.f};

    // --- prologue: stage tiles 0,1,2 into buffers 0,1,2 (15 loads/wave) ---
#pragma unroll
    for (int t = 0; t < 3; ++t) {
        const int kofs = t * 64;
        unsigned short* base = &Sm[t * BUFE];
        gl2lds16(Asg + kofs, base + dstA);
        gl2lds16(Bsg0 + kofs, base + dstB);
        gl2lds16(Bsg1 + kofs, base + dstB + 512);
        gl2lds16(Bsg2 + kofs, base + dstB + 1024);
        gl2lds16(Bsg3 + kofs, base + dstB + 1536);
    }

    int cur = 0;
#pragma unroll 1
    for (int t = 0; t < 32; ++t) {
        // stage(t) landed; stage(t+1),(t+2) = 10 loads stay in flight
        asm volatile("s_waitcnt vmcnt(10)" ::: "memory");
        __builtin_amdgcn_s_barrier();
        asm volatile("" ::: "memory");
        const unsigned short* sb = &Sm[cur * BUFE];
#pragma unroll
        for (int s = 0; s < 2; ++s) {
            bf16x8 a0 = *(const bf16x8*)(sb + aoff[0][s]);
            bf16x8 a1 = *(const bf16x8*)(sb + aoff[1][s]);
            bf16x8 b0 = *(const bf16x8*)(sb + boff[0][s]);
            bf16x8 b1 = *(const bf16x8*)(sb + boff[1][s]);
            acc[0][0] = __builtin_amdgcn_mfma_f32_16x16x32_bf16(a0, b0, acc[0][0], 0, 0, 0);
            acc[1][0] = __builtin_amdgcn_mfma_f32_16x16x32_bf16(a1, b0, acc[1][0], 0, 0, 0);
            acc[0][1] = __builtin_amdgcn_mfma_f32_16x16x32_bf16(a0, b1, acc[0][1], 0, 0, 0);
            acc[1][1] = __builtin_amdgcn_mfma_f32_16x16x32_bf16(a1, b1, acc[1][1], 0, 0, 0);
        }
        asm volatile("" ::: "memory");
        __builtin_amdgcn_s_barrier();                 // all waves done reading buf cur
        asm volatile("" ::: "memory");
        // stage tile (t+3)&31 into buffer cur (wraps at tail: keeps vmcnt
        // uniform; stale data never read).
        {
            const int kofs = ((t + 3) & 31) * 64;
            unsigned short* base = &Sm[cur * BUFE];
            gl2lds16(Asg + kofs, base + dstA);
            gl2lds16(Bsg0 + kofs, base + dstB);
            gl2lds16(Bsg1 + kofs, base + dstB + 512);
            gl2lds16(Bsg2 + kofs, base + dstB + 1024);
            gl2lds16(Bsg3 + kofs, base + dstB + 1536);
        }
        cur = (cur == 2) ? 0 : cur + 1;
    }

    // epilogue. C/D: col = lane&15, row = quad*4 + reg
    const int rb = row0 + q * 4;
    float dsc[2][4];
#pragma unroll
    for (int mi = 0; mi < 2; ++mi)
#pragma unroll
        for (int r = 0; r < 4; ++r) dsc[mi][r] = dinv[rb + mi * 16 + r];
#pragma unroll
    for (int mi = 0; mi < 2; ++mi) {
#pragma unroll
        for (int nj = 0; nj < 2; ++nj) {
            const int f = wave * 32 + nj * 16 + n_;
#pragma unroll
            for (int r = 0; r < 4; ++r) {
                const size_t gr = (size_t)(rb + mi * 16 + r);
                float v = acc[mi][nj][r] * dsc[mi][r];    // * dinv_i
                if (MODE == 2) v += bf2f(resid[gr * 128 + f]);
                if (OUT32) ((float*)outp)[gr * 128 + f] = v;
                else ((unsigned short*)outp)[gr * 128 + f] = f2bf(v);
            }
        }
    }
}

extern "C" void kernel_launch(void* const* d_in, const int* in_sizes, int n_in,
                              void* d_out, int out_size, void* d_ws, size_t ws_size,
                              hipStream_t stream) {
    const float* X   = (const float*)d_in[0];
    const float* adj = (const float*)d_in[1];
    const float* W1  = (const float*)d_in[2];
    const float* b1  = (const float*)d_in[3];
    const float* W2  = (const float*)d_in[4];
    const float* b2  = (const float*)d_in[5];
    const float* W3  = (const float*)d_in[6];
    const float* b3  = (const float*)d_in[7];

    // ws: adjb @0 (64 MiB) | dinv @64M (64K) | biasf @64M+64K | WT @64M+128K
    //     (96K) | HsT @64M+256K (4M) | Xa @68M+256K (4M) | X2 @72M+256K (4M)
    char* ws = (char*)d_ws;
    unsigned short* adjb  = (unsigned short*)ws;
    float*          dinv  = (float*)(ws + (64u << 20));
    float*          biasf = (float*)(ws + (64u << 20) + (64u << 10));
    unsigned short* WT    = (unsigned short*)(ws + (64u << 20) + (128u << 10));
    unsigned short* HsT   = (unsigned short*)(ws + (64u << 20) + (256u << 10));
    unsigned short* Xa    = (unsigned short*)(ws + (68u << 20) + (256u << 10));
    unsigned short* X2    = (unsigned short*)(ws + (72u << 20) + (256u << 10));

    k_pre<<<16578, 256, 0, stream>>>(adj, W1, W2, W3, b1, b2, b3, dinv, adjb, WT, biasf);

    // layer 1
    k_gxw<1><<<512, 256, 0, stream>>>(X, WT, biasf, dinv, HsT);
    k_gah<1, 0><<<512, 256, 0, stream>>>(adjb, HsT, dinv, nullptr, Xa);
    // layer 2 (residual = Xa)
    k_gxw<0><<<512, 256, 0, stream>>>(Xa, WT + 16384, biasf + 128, dinv, HsT);
    k_gah<2, 0><<<512, 256, 0, stream>>>(adjb, HsT, dinv, Xa, X2);
    // layer 3 -> fp32 out
    k_gxw<0><<<512, 256, 0, stream>>>(X2, WT + 32768, biasf + 256, dinv, HsT);
    k_gah<1, 1><<<512, 256, 0, stream>>>(adjb, HsT, dinv, nullptr, (float*)d_out);
}